// Round 4
// baseline (78.719 us; speedup 1.0000x reference)
//
#include <hip/hip_runtime.h>
#include <math.h>

#define NN 1024
#define DHH 32
#define DEE 16
#define TT 8
#define NOBS_ 64
#define ADIM_ 10
#define NSPLIT 2   // blocks per row in edge kernel

typedef _Float16 h4 __attribute__((ext_vector_type(4)));
typedef float f4 __attribute__((ext_vector_type(4)));

__device__ __forceinline__ float sig_(float x) { return 1.0f / (1.0f + __expf(-x)); }
__device__ __forceinline__ float tanh_(float x) { return 1.0f - 2.0f / (1.0f + __expf(2.0f * x)); }

// y[i][d] = relu(h[i] . W_out[d] + b_out[d]); also emit f16 copy for MFMA B-frags.
__global__ __launch_bounds__(256) void y_kernel(const float* __restrict__ h,
                                                const float* __restrict__ W_out,
                                                const float* __restrict__ b_out,
                                                float* __restrict__ y,
                                                _Float16* __restrict__ y_h) {
  int gid = blockIdx.x * 256 + threadIdx.x;
  int i = gid >> 4, d = gid & 15;
  const float* hp = h + i * DHH;
  const float* wp = W_out + d * DHH;
  float s = b_out[d];
#pragma unroll
  for (int q = 0; q < DHH; ++q) s = fmaf(hp[q], wp[q], s);
  s = fmaxf(s, 0.0f);
  y[gid] = s;
  y_h[gid] = (_Float16)s;
}

// base[i][k] = b_e[t_i][k] + r*w_ih_e[t_i][k][32] + sum_d w_ih_e[t_i][k][d]*y[i][d]
__global__ __launch_bounds__(256) void prep_kernel(const float* __restrict__ y,
                                                   const int* __restrict__ types,
                                                   const float* __restrict__ w_ih_e,
                                                   const float* __restrict__ b_e,
                                                   const float* __restrict__ rs,
                                                   float* __restrict__ base) {
  int gid = blockIdx.x * 256 + threadIdx.x;
  int i = gid / 48, k = gid - (gid / 48) * 48;
  int t = types[i];
  const float* w = w_ih_e + (size_t)(t * 48 + k) * 33;
  const float* yp = y + i * DEE;
  float s = b_e[t * 48 + k] + rs[0] * w[32];
#pragma unroll
  for (int q = 0; q < DEE; ++q) s = fmaf(w[q], yp[q], s);
  base[gid] = s;
}

// MFMA edge GRU, gj folded into matrix pipe. Block b: row i = b>>1, half s = b&1.
// Per 16-edge tile: 6x mfma_f32_16x16x16_f16 (r,z merged ig+hg; n split for reset scaling).
// D layout: lane -> edge j0+(lane&15), dims (lane>>4)*4+q.
__global__ __launch_bounds__(256, 6) void edge_kernel(
    const float* __restrict__ e, const int* __restrict__ A,
    const float* __restrict__ w_hh_e, const float* __restrict__ w_ih_e,
    const float* __restrict__ bn_e, const int* __restrict__ types,
    const float* __restrict__ base, const _Float16* __restrict__ yh,
    float* __restrict__ e_new, float* __restrict__ rowsum_part) {
  __shared__ float red[4][16];
  const int b = blockIdx.x;
  const int i = b >> 1;
  const int s = b & 1;
  const int tid = threadIdx.x;
  const int lane = tid & 63, wid = tid >> 6;
  const int lj = lane & 15;   // edge index within tile (A/B N-index, D col)
  const int kg = lane >> 4;   // K chunk (A/B), dim chunk (D rows)
  const int t = types[i];

  // hh A-frags: W_hh[gate*16+lj][kg*4+q]  (contiguous -> f4 loads)
  const float* Wt = w_hh_e + (size_t)t * 768;
  h4 ar, az, an;
  {
    f4 vr = *(const f4*)(Wt + lj * 16 + kg * 4);
    f4 vz = *(const f4*)(Wt + (16 + lj) * 16 + kg * 4);
    f4 vn = *(const f4*)(Wt + (32 + lj) * 16 + kg * 4);
#pragma unroll
    for (int q = 0; q < 4; ++q) {
      ar[q] = (_Float16)vr[q]; az[q] = (_Float16)vz[q]; an[q] = (_Float16)vn[q];
    }
  }
  // ih(y_j) A-frags: w_ih_e[t][gate*16+lj][16 + kg*4+q]  (row stride 33 -> scalar loads)
  const float* W2 = w_ih_e + (size_t)t * 48 * 33 + 16;
  h4 cr, cz, cn;
#pragma unroll
  for (int q = 0; q < 4; ++q) {
    cr[q] = (_Float16)W2[lj * 33 + kg * 4 + q];
    cz[q] = (_Float16)W2[(16 + lj) * 33 + kg * 4 + q];
    cn[q] = (_Float16)W2[(32 + lj) * 33 + kg * 4 + q];
  }

  const f4 bsr = *(const f4*)(base + i * 48 + kg * 4);
  const f4 bsz = *(const f4*)(base + i * 48 + 16 + kg * 4);
  const f4 bsn = *(const f4*)(base + i * 48 + 32 + kg * 4);
  const f4 bnv = *(const f4*)(bn_e + t * 16 + kg * 4);

  const int jb = s * 512 + wid * 128 + lj;   // this lane's edge for tile tt is jb + tt*16
  const size_t erow = (size_t)i * NN;
  f4 acc = {0.0f, 0.0f, 0.0f, 0.0f};
  const f4 zero = {0.0f, 0.0f, 0.0f, 0.0f};

#define LOADT(tt, ev, yv, aij)                                            \
  {                                                                       \
    const int j = jb + (tt) * 16;                                         \
    ev = *(const f4*)(e + (erow + j) * 16 + kg * 4);                      \
    yv = *(const h4*)(yh + j * 16 + kg * 4);                              \
    aij = (float)A[erow + j];                                             \
  }

#define COMPT(tt, ev, yv, aij)                                            \
  {                                                                       \
    h4 bf;                                                                \
    _Pragma("unroll") for (int q = 0; q < 4; ++q) bf[q] = (_Float16)ev[q];\
    f4 dr = __builtin_amdgcn_mfma_f32_16x16x16f16(ar, bf, zero, 0, 0, 0); \
    f4 dz = __builtin_amdgcn_mfma_f32_16x16x16f16(az, bf, zero, 0, 0, 0); \
    f4 dh = __builtin_amdgcn_mfma_f32_16x16x16f16(an, bf, zero, 0, 0, 0); \
    dr = __builtin_amdgcn_mfma_f32_16x16x16f16(cr, yv, dr, 0, 0, 0);      \
    dz = __builtin_amdgcn_mfma_f32_16x16x16f16(cz, yv, dz, 0, 0, 0);      \
    f4 di = __builtin_amdgcn_mfma_f32_16x16x16f16(cn, yv, zero, 0, 0, 0); \
    _Pragma("unroll") for (int q = 0; q < 4; ++q)                         \
        acc[q] = fmaf(ev[q], aij, acc[q]);                                \
    float outv[4];                                                        \
    _Pragma("unroll") for (int q = 0; q < 4; ++q) {                       \
      const float rg = sig_(bsr[q] + dr[q]);                              \
      const float zg = sig_(bsz[q] + dz[q]);                              \
      const float ng = tanh_(bsn[q] + di[q] + rg * (dh[q] + bnv[q]));     \
      outv[q] = ng + zg * (ev[q] - ng);                                   \
    }                                                                     \
    float* op = e_new + (erow + (jb + (tt) * 16)) * 16 + kg * 4;          \
    __builtin_memcpy(op, outv, 16);                                       \
  }

  // 2-deep software pipeline over 8 tiles
  f4 evA, evB; h4 yvA, yvB; float aA, aB;
  LOADT(0, evA, yvA, aA)
  LOADT(1, evB, yvB, aB)
#pragma unroll
  for (int it = 0; it < 4; ++it) {
    f4 evC; h4 yvC; float aC;
    if (it < 3) { LOADT(2 * it + 2, evC, yvC, aC) }
    COMPT(2 * it, evA, yvA, aA)
    if (it < 3) { LOADT(2 * it + 3, evA, yvA, aA) }
    COMPT(2 * it + 1, evB, yvB, aB)
    if (it < 3) { evB = evA; yvB = yvA; aB = aA; evA = evC; yvA = yvC; aA = aC; }
  }
#undef LOADT
#undef COMPT

  // acc[q] = partial sum over this lane's 8 j's of e[i][j][kg*4+q]*A[i][j];
  // reduce over the 16 lanes of each kg-group.
#pragma unroll
  for (int m = 1; m <= 8; m <<= 1) {
#pragma unroll
    for (int q = 0; q < 4; ++q) acc[q] += __shfl_xor(acc[q], m, 64);
  }
  if (lj == 0) {
#pragma unroll
    for (int q = 0; q < 4; ++q) red[wid][kg * 4 + q] = acc[q];
  }
  __syncthreads();
  if (tid < 16)
    rowsum_part[((size_t)i * NSPLIT + s) * 16 + tid] =
        red[0][tid] + red[1][tid] + red[2][tid] + red[3][tid];
}

// Node GRU (32 threads per node, 8 nodes per block) + argmax in block 0 thread 0.
__global__ __launch_bounds__(256) void node_kernel(
    const float* __restrict__ obs, const float* __restrict__ h,
    const int* __restrict__ types, const float* __restrict__ w_ih_n,
    const float* __restrict__ w_hh_n, const float* __restrict__ b_n,
    const float* __restrict__ bn_n, const float* __restrict__ y,
    const float* __restrict__ rowsum_part, float* __restrict__ out) {
  const int tid = threadIdx.x;
  const int node = blockIdx.x * 8 + (tid >> 5);
  const int d = tid & 31;
  const int t = types[node];
  float x[16];
#pragma unroll
  for (int q = 0; q < 16; ++q) {
    const float* rp = rowsum_part + (size_t)node * NSPLIT * 16 + q;
    float rs = rp[0] + rp[16];
    x[q] = y[node * 16 + q] * rs;
  }
  if (node < NOBS_) x[0] = obs[node];
  const float* wi = w_ih_n + (size_t)t * 96 * 16;
  const float* wh = w_hh_n + (size_t)t * 96 * 32;
  const float* hp = h + node * 32;
  float ir = b_n[t * 96 + d], iz = b_n[t * 96 + 32 + d], in_ = b_n[t * 96 + 64 + d];
#pragma unroll
  for (int q = 0; q < 16; ++q) {
    ir = fmaf(wi[d * 16 + q], x[q], ir);
    iz = fmaf(wi[(32 + d) * 16 + q], x[q], iz);
    in_ = fmaf(wi[(64 + d) * 16 + q], x[q], in_);
  }
  float hr = 0.0f, hz = 0.0f, hn = 0.0f;
#pragma unroll
  for (int q = 0; q < 32; ++q) {
    hr = fmaf(wh[d * 32 + q], hp[q], hr);
    hz = fmaf(wh[(32 + d) * 32 + q], hp[q], hz);
    hn = fmaf(wh[(64 + d) * 32 + q], hp[q], hn);
  }
  float rg = sig_(ir + hr), zg = sig_(iz + hz);
  float ng = tanh_(in_ + rg * (hn + bn_n[t * 32 + d]));
  out[1 + node * 32 + d] = ng + zg * (hp[d] - ng);

  if (blockIdx.x == 0 && tid == 0) {
    int bi = 0;
    float best = y[(NN - ADIM_) * 16];
    for (int l = 1; l < ADIM_; ++l) {
      float v = y[(NN - ADIM_ + l) * 16];
      if (v > best) { best = v; bi = l; }
    }
    out[0] = (float)bi;
  }
}

extern "C" void kernel_launch(void* const* d_in, const int* in_sizes, int n_in,
                              void* d_out, int out_size, void* d_ws, size_t ws_size,
                              hipStream_t stream) {
  const float* obs   = (const float*)d_in[0];
  const float* h     = (const float*)d_in[1];
  const int*   types = (const int*)d_in[2];
  const float* e     = (const float*)d_in[3];
  const int*   A     = (const int*)d_in[4];
  const float* r     = (const float*)d_in[5];
  const float* w_ih_n = (const float*)d_in[6];
  const float* w_hh_n = (const float*)d_in[7];
  const float* b_n    = (const float*)d_in[8];
  const float* bn_n   = (const float*)d_in[9];
  const float* W_out  = (const float*)d_in[10];
  const float* b_out  = (const float*)d_in[11];
  const float* w_ih_e = (const float*)d_in[12];
  const float* w_hh_e = (const float*)d_in[13];
  const float* b_e    = (const float*)d_in[14];
  const float* bn_e   = (const float*)d_in[15];

  float* ws = (float*)d_ws;
  float* y_buf       = ws;                     // 1024*16  f32
  float* base        = y_buf + 16384;          // 1024*48  f32
  float* rowsum_part = base + 49152;           // 1024*2*16 f32
  _Float16* y_h      = (_Float16*)(rowsum_part + 32768);  // 1024*16 f16

  float* out   = (float*)d_out;
  float* out_e = out + 1 + NN * DHH;           // e_new region (d_out + 32769)

  y_kernel<<<64, 256, 0, stream>>>(h, W_out, b_out, y_buf, y_h);
  prep_kernel<<<192, 256, 0, stream>>>(y_buf, types, w_ih_e, b_e, r, base);
  edge_kernel<<<NN * NSPLIT, 256, 0, stream>>>(e, A, w_hh_e, w_ih_e, bn_e, types,
                                               base, y_h, out_e, rowsum_part);
  node_kernel<<<128, 256, 0, stream>>>(obs, h, types, w_ih_n, w_hh_n, b_n, bn_n,
                                       y_buf, rowsum_part, out);
}

// Round 5
// 55.015 us; speedup vs baseline: 1.4309x; 1.4309x over previous
//
#include <hip/hip_runtime.h>
#include <math.h>

#define NN 1024
#define DHH 32
#define DEE 16
#define TT 8
#define NOBS_ 64
#define ADIM_ 10
#define NSPLIT 2   // blocks per row in edge kernel

typedef _Float16 h4 __attribute__((ext_vector_type(4)));
typedef float f4 __attribute__((ext_vector_type(4)));

__device__ __forceinline__ float sig_(float x) { return 1.0f / (1.0f + __expf(-x)); }
__device__ __forceinline__ float tanh_(float x) { return 1.0f - 2.0f / (1.0f + __expf(2.0f * x)); }

// y[i][d] = relu(h[i] . W_out[d] + b_out[d]); also emit f16 copy for MFMA B-frags.
__global__ __launch_bounds__(256) void y_kernel(const float* __restrict__ h,
                                                const float* __restrict__ W_out,
                                                const float* __restrict__ b_out,
                                                float* __restrict__ y,
                                                _Float16* __restrict__ y_h) {
  int gid = blockIdx.x * 256 + threadIdx.x;
  int i = gid >> 4, d = gid & 15;
  const float* hp = h + i * DHH;
  const float* wp = W_out + d * DHH;
  float s = b_out[d];
#pragma unroll
  for (int q = 0; q < DHH; ++q) s = fmaf(hp[q], wp[q], s);
  s = fmaxf(s, 0.0f);
  y[gid] = s;
  y_h[gid] = (_Float16)s;
}

// base[i][k] = b_e[t_i][k] + r*w_ih_e[t_i][k][32] + sum_d w_ih_e[t_i][k][d]*y[i][d]
__global__ __launch_bounds__(256) void prep_kernel(const float* __restrict__ y,
                                                   const int* __restrict__ types,
                                                   const float* __restrict__ w_ih_e,
                                                   const float* __restrict__ b_e,
                                                   const float* __restrict__ rs,
                                                   float* __restrict__ base) {
  int gid = blockIdx.x * 256 + threadIdx.x;
  int i = gid / 48, k = gid - (gid / 48) * 48;
  int t = types[i];
  const float* w = w_ih_e + (size_t)(t * 48 + k) * 33;
  const float* yp = y + i * DEE;
  float s = b_e[t * 48 + k] + rs[0] * w[32];
#pragma unroll
  for (int q = 0; q < DEE; ++q) s = fmaf(w[q], yp[q], s);
  base[gid] = s;
}

// MFMA edge GRU, gj folded into matrix pipe. Block b: row i = b>>1, half s = b&1.
// Per 16-edge tile: 6x mfma_f32_16x16x16_f16 (r,z merged ig+hg; n split for reset scaling).
// D layout: lane -> edge j0+(lane&15), dims (lane>>4)*4+q.
__global__ __launch_bounds__(256) void edge_kernel(
    const float* __restrict__ e, const int* __restrict__ A,
    const float* __restrict__ w_hh_e, const float* __restrict__ w_ih_e,
    const float* __restrict__ bn_e, const int* __restrict__ types,
    const float* __restrict__ base, const _Float16* __restrict__ yh,
    float* __restrict__ e_new, float* __restrict__ rowsum_part) {
  __shared__ float red[4][16];
  const int b = blockIdx.x;
  const int i = b >> 1;
  const int s = b & 1;
  const int tid = threadIdx.x;
  const int lane = tid & 63, wid = tid >> 6;
  const int lj = lane & 15;   // edge index within tile (A/B N-index, D col)
  const int kg = lane >> 4;   // K chunk (A/B), dim chunk (D rows)
  const int t = types[i];

  // hh A-frags: W_hh[gate*16+lj][kg*4+q]  (contiguous -> f4 loads)
  const float* Wt = w_hh_e + (size_t)t * 768;
  h4 ar, az, an;
  {
    f4 vr = *(const f4*)(Wt + lj * 16 + kg * 4);
    f4 vz = *(const f4*)(Wt + (16 + lj) * 16 + kg * 4);
    f4 vn = *(const f4*)(Wt + (32 + lj) * 16 + kg * 4);
#pragma unroll
    for (int q = 0; q < 4; ++q) {
      ar[q] = (_Float16)vr[q]; az[q] = (_Float16)vz[q]; an[q] = (_Float16)vn[q];
    }
  }
  // ih(y_j) A-frags: w_ih_e[t][gate*16+lj][16 + kg*4+q]  (row stride 33)
  const float* W2 = w_ih_e + (size_t)t * 48 * 33 + 16;
  h4 cr, cz, cn;
#pragma unroll
  for (int q = 0; q < 4; ++q) {
    cr[q] = (_Float16)W2[lj * 33 + kg * 4 + q];
    cz[q] = (_Float16)W2[(16 + lj) * 33 + kg * 4 + q];
    cn[q] = (_Float16)W2[(32 + lj) * 33 + kg * 4 + q];
  }

  const f4 bsr = *(const f4*)(base + i * 48 + kg * 4);
  const f4 bsz = *(const f4*)(base + i * 48 + 16 + kg * 4);
  const f4 bsn = *(const f4*)(base + i * 48 + 32 + kg * 4);
  const f4 bnv = *(const f4*)(bn_e + t * 16 + kg * 4);

  const int jb = s * 512 + wid * 128 + lj;   // this lane's edge for tile tt is jb + tt*16
  const size_t erow = (size_t)i * NN;
  f4 acc = {0.0f, 0.0f, 0.0f, 0.0f};
  const f4 zero = {0.0f, 0.0f, 0.0f, 0.0f};

#pragma unroll
  for (int tt = 0; tt < 8; ++tt) {
    const int j = jb + tt * 16;
    const size_t eoff = (erow + j) * 16 + kg * 4;
    const f4 ev = *(const f4*)(e + eoff);
    const h4 yv = *(const h4*)(yh + j * 16 + kg * 4);
    const float aij = (float)A[erow + j];

    h4 bf;
#pragma unroll
    for (int q = 0; q < 4; ++q) bf[q] = (_Float16)ev[q];

    f4 dr = __builtin_amdgcn_mfma_f32_16x16x16f16(ar, bf, zero, 0, 0, 0);
    f4 dz = __builtin_amdgcn_mfma_f32_16x16x16f16(az, bf, zero, 0, 0, 0);
    f4 dh = __builtin_amdgcn_mfma_f32_16x16x16f16(an, bf, zero, 0, 0, 0);
    dr = __builtin_amdgcn_mfma_f32_16x16x16f16(cr, yv, dr, 0, 0, 0);
    dz = __builtin_amdgcn_mfma_f32_16x16x16f16(cz, yv, dz, 0, 0, 0);
    const f4 di = __builtin_amdgcn_mfma_f32_16x16x16f16(cn, yv, zero, 0, 0, 0);

#pragma unroll
    for (int q = 0; q < 4; ++q) acc[q] = fmaf(ev[q], aij, acc[q]);

    float* op = e_new + eoff;
#pragma unroll
    for (int q = 0; q < 4; ++q) {
      const float rg = sig_(bsr[q] + dr[q]);
      const float zg = sig_(bsz[q] + dz[q]);
      const float ng = tanh_(bsn[q] + di[q] + rg * (dh[q] + bnv[q]));
      op[q] = ng + zg * (ev[q] - ng);
    }
  }

  // acc[q] = partial sum over this lane's 8 j's of e[i][j][kg*4+q]*A[i][j];
  // reduce over the 16 lanes of each kg-group.
#pragma unroll
  for (int m = 1; m <= 8; m <<= 1) {
#pragma unroll
    for (int q = 0; q < 4; ++q) acc[q] += __shfl_xor(acc[q], m, 64);
  }
  if (lj == 0) {
#pragma unroll
    for (int q = 0; q < 4; ++q) red[wid][kg * 4 + q] = acc[q];
  }
  __syncthreads();
  if (tid < 16)
    rowsum_part[((size_t)i * NSPLIT + s) * 16 + tid] =
        red[0][tid] + red[1][tid] + red[2][tid] + red[3][tid];
}

// Node GRU (32 threads per node, 8 nodes per block) + argmax in block 0 thread 0.
__global__ __launch_bounds__(256) void node_kernel(
    const float* __restrict__ obs, const float* __restrict__ h,
    const int* __restrict__ types, const float* __restrict__ w_ih_n,
    const float* __restrict__ w_hh_n, const float* __restrict__ b_n,
    const float* __restrict__ bn_n, const float* __restrict__ y,
    const float* __restrict__ rowsum_part, float* __restrict__ out) {
  const int tid = threadIdx.x;
  const int node = blockIdx.x * 8 + (tid >> 5);
  const int d = tid & 31;
  const int t = types[node];
  float x[16];
#pragma unroll
  for (int q = 0; q < 16; ++q) {
    const float* rp = rowsum_part + (size_t)node * NSPLIT * 16 + q;
    float rs = rp[0] + rp[16];
    x[q] = y[node * 16 + q] * rs;
  }
  if (node < NOBS_) x[0] = obs[node];
  const float* wi = w_ih_n + (size_t)t * 96 * 16;
  const float* wh = w_hh_n + (size_t)t * 96 * 32;
  const float* hp = h + node * 32;
  float ir = b_n[t * 96 + d], iz = b_n[t * 96 + 32 + d], in_ = b_n[t * 96 + 64 + d];
#pragma unroll
  for (int q = 0; q < 16; ++q) {
    ir = fmaf(wi[d * 16 + q], x[q], ir);
    iz = fmaf(wi[(32 + d) * 16 + q], x[q], iz);
    in_ = fmaf(wi[(64 + d) * 16 + q], x[q], in_);
  }
  float hr = 0.0f, hz = 0.0f, hn = 0.0f;
#pragma unroll
  for (int q = 0; q < 32; ++q) {
    hr = fmaf(wh[d * 32 + q], hp[q], hr);
    hz = fmaf(wh[(32 + d) * 32 + q], hp[q], hz);
    hn = fmaf(wh[(64 + d) * 32 + q], hp[q], hn);
  }
  float rg = sig_(ir + hr), zg = sig_(iz + hz);
  float ng = tanh_(in_ + rg * (hn + bn_n[t * 32 + d]));
  out[1 + node * 32 + d] = ng + zg * (hp[d] - ng);

  if (blockIdx.x == 0 && tid == 0) {
    int bi = 0;
    float best = y[(NN - ADIM_) * 16];
    for (int l = 1; l < ADIM_; ++l) {
      float v = y[(NN - ADIM_ + l) * 16];
      if (v > best) { best = v; bi = l; }
    }
    out[0] = (float)bi;
  }
}

extern "C" void kernel_launch(void* const* d_in, const int* in_sizes, int n_in,
                              void* d_out, int out_size, void* d_ws, size_t ws_size,
                              hipStream_t stream) {
  const float* obs   = (const float*)d_in[0];
  const float* h     = (const float*)d_in[1];
  const int*   types = (const int*)d_in[2];
  const float* e     = (const float*)d_in[3];
  const int*   A     = (const int*)d_in[4];
  const float* r     = (const float*)d_in[5];
  const float* w_ih_n = (const float*)d_in[6];
  const float* w_hh_n = (const float*)d_in[7];
  const float* b_n    = (const float*)d_in[8];
  const float* bn_n   = (const float*)d_in[9];
  const float* W_out  = (const float*)d_in[10];
  const float* b_out  = (const float*)d_in[11];
  const float* w_ih_e = (const float*)d_in[12];
  const float* w_hh_e = (const float*)d_in[13];
  const float* b_e    = (const float*)d_in[14];
  const float* bn_e   = (const float*)d_in[15];

  float* ws = (float*)d_ws;
  float* y_buf       = ws;                     // 1024*16  f32
  float* base        = y_buf + 16384;          // 1024*48  f32
  float* rowsum_part = base + 49152;           // 1024*2*16 f32
  _Float16* y_h      = (_Float16*)(rowsum_part + 32768);  // 1024*16 f16

  float* out   = (float*)d_out;
  float* out_e = out + 1 + NN * DHH;           // e_new region (d_out + 32769)

  y_kernel<<<64, 256, 0, stream>>>(h, W_out, b_out, y_buf, y_h);
  prep_kernel<<<192, 256, 0, stream>>>(y_buf, types, w_ih_e, b_e, r, base);
  edge_kernel<<<NN * NSPLIT, 256, 0, stream>>>(e, A, w_hh_e, w_ih_e, bn_e, types,
                                               base, y_h, out_e, rowsum_part);
  node_kernel<<<128, 256, 0, stream>>>(obs, h, types, w_ih_n, w_hh_n, b_n, bn_n,
                                       y_buf, rowsum_part, out);
}

// Round 6
// 44.079 us; speedup vs baseline: 1.7859x; 1.2481x over previous
//
#include <hip/hip_runtime.h>
#include <math.h>

#define NN 1024
#define DHH 32
#define DEE 16
#define TT 8
#define NOBS_ 64
#define ADIM_ 10
#define NSPLIT 2   // blocks per row in edge kernel

typedef _Float16 h4 __attribute__((ext_vector_type(4)));
typedef float f4 __attribute__((ext_vector_type(4)));

// 1-ulp hardware reciprocal: avoids the ~10-instr IEEE division expansion.
__device__ __forceinline__ float rcp_(float x) { return __builtin_amdgcn_rcpf(x); }
__device__ __forceinline__ float sig_(float x) { return rcp_(1.0f + __expf(-x)); }
__device__ __forceinline__ float tanh_(float x) { return 1.0f - 2.0f * rcp_(1.0f + __expf(2.0f * x)); }

// y[i][d] = relu(h[i] . W_out[d] + b_out[d]); also emit f16 copy for MFMA B-frags.
__global__ __launch_bounds__(256) void y_kernel(const float* __restrict__ h,
                                                const float* __restrict__ W_out,
                                                const float* __restrict__ b_out,
                                                float* __restrict__ y,
                                                _Float16* __restrict__ y_h) {
  int gid = blockIdx.x * 256 + threadIdx.x;
  int i = gid >> 4, d = gid & 15;
  const float* hp = h + i * DHH;
  const float* wp = W_out + d * DHH;
  float s = b_out[d];
#pragma unroll
  for (int q = 0; q < DHH; ++q) s = fmaf(hp[q], wp[q], s);
  s = fmaxf(s, 0.0f);
  y[gid] = s;
  y_h[gid] = (_Float16)s;
}

// base[i][k] = b_e[t_i][k] + r*w_ih_e[t_i][k][32] + sum_d w_ih_e[t_i][k][d]*y[i][d]
__global__ __launch_bounds__(256) void prep_kernel(const float* __restrict__ y,
                                                   const int* __restrict__ types,
                                                   const float* __restrict__ w_ih_e,
                                                   const float* __restrict__ b_e,
                                                   const float* __restrict__ rs,
                                                   float* __restrict__ base) {
  int gid = blockIdx.x * 256 + threadIdx.x;
  int i = gid / 48, k = gid - (gid / 48) * 48;
  int t = types[i];
  const float* w = w_ih_e + (t * 48 + k) * 33;
  const float* yp = y + i * DEE;
  float s = b_e[t * 48 + k] + rs[0] * w[32];
#pragma unroll
  for (int q = 0; q < DEE; ++q) s = fmaf(w[q], yp[q], s);
  base[gid] = s;
}

// MFMA edge GRU, gj folded into matrix pipe. Block b: row i = b>>1, half s = b&1.
// Per 16-edge tile: 6x mfma_f32_16x16x16_f16 (r,z merged ig+hg; n split for reset scaling).
// D layout: lane -> edge j0+(lane&15), dims (lane>>4)*4+q.
__global__ __launch_bounds__(256) void edge_kernel(
    const float* __restrict__ e, const int* __restrict__ A,
    const float* __restrict__ w_hh_e, const float* __restrict__ w_ih_e,
    const float* __restrict__ bn_e, const int* __restrict__ types,
    const float* __restrict__ base, const _Float16* __restrict__ yh,
    float* __restrict__ e_new, float* __restrict__ rowsum_part) {
  __shared__ float red[4][16];
  const int b = blockIdx.x;
  const int i = b >> 1;
  const int s = b & 1;
  const int tid = threadIdx.x;
  const int lane = tid & 63, wid = tid >> 6;
  const int lj = lane & 15;   // edge index within tile (A/B N-index, D col)
  const int kg = lane >> 4;   // K chunk (A/B), dim chunk (D rows)
  const int t = types[i];

  // hh A-frags: W_hh[gate*16+lj][kg*4+q]  (contiguous -> f4 loads)
  const float* Wt = w_hh_e + t * 768;
  h4 ar, az, an;
  {
    f4 vr = *(const f4*)(Wt + lj * 16 + kg * 4);
    f4 vz = *(const f4*)(Wt + (16 + lj) * 16 + kg * 4);
    f4 vn = *(const f4*)(Wt + (32 + lj) * 16 + kg * 4);
#pragma unroll
    for (int q = 0; q < 4; ++q) {
      ar[q] = (_Float16)vr[q]; az[q] = (_Float16)vz[q]; an[q] = (_Float16)vn[q];
    }
  }
  // ih(y_j) A-frags: w_ih_e[t][gate*16+lj][16 + kg*4+q]  (row stride 33)
  const float* W2 = w_ih_e + t * 48 * 33 + 16;
  h4 cr, cz, cn;
#pragma unroll
  for (int q = 0; q < 4; ++q) {
    cr[q] = (_Float16)W2[lj * 33 + kg * 4 + q];
    cz[q] = (_Float16)W2[(16 + lj) * 33 + kg * 4 + q];
    cn[q] = (_Float16)W2[(32 + lj) * 33 + kg * 4 + q];
  }

  const f4 bsr = *(const f4*)(base + i * 48 + kg * 4);
  const f4 bsz = *(const f4*)(base + i * 48 + 16 + kg * 4);
  const f4 bsn = *(const f4*)(base + i * 48 + 32 + kg * 4);
  const f4 bnv = *(const f4*)(bn_e + t * 16 + kg * 4);

  const int jb = s * 512 + wid * 128 + lj;   // this lane's edge for tile tt is jb + tt*16
  const int erow = i * NN;                   // 32-bit offsets throughout the hot loop
  f4 acc = {0.0f, 0.0f, 0.0f, 0.0f};
  const f4 zero = {0.0f, 0.0f, 0.0f, 0.0f};

#pragma unroll
  for (int tt = 0; tt < 8; ++tt) {
    const int j = jb + tt * 16;
    const int eoff = (erow + j) * 16 + kg * 4;
    const f4 ev = *(const f4*)(e + eoff);
    const h4 yv = *(const h4*)(yh + j * 16 + kg * 4);
    const float aij = (float)A[erow + j];

    h4 bf;
#pragma unroll
    for (int q = 0; q < 4; ++q) bf[q] = (_Float16)ev[q];

    f4 dr = __builtin_amdgcn_mfma_f32_16x16x16f16(ar, bf, zero, 0, 0, 0);
    f4 dz = __builtin_amdgcn_mfma_f32_16x16x16f16(az, bf, zero, 0, 0, 0);
    f4 dh = __builtin_amdgcn_mfma_f32_16x16x16f16(an, bf, zero, 0, 0, 0);
    dr = __builtin_amdgcn_mfma_f32_16x16x16f16(cr, yv, dr, 0, 0, 0);
    dz = __builtin_amdgcn_mfma_f32_16x16x16f16(cz, yv, dz, 0, 0, 0);
    const f4 di = __builtin_amdgcn_mfma_f32_16x16x16f16(cn, yv, zero, 0, 0, 0);

#pragma unroll
    for (int q = 0; q < 4; ++q) acc[q] = fmaf(ev[q], aij, acc[q]);

    float* op = e_new + eoff;
#pragma unroll
    for (int q = 0; q < 4; ++q) {
      const float rg = sig_(bsr[q] + dr[q]);
      const float zg = sig_(bsz[q] + dz[q]);
      const float ng = tanh_(bsn[q] + di[q] + rg * (dh[q] + bnv[q]));
      op[q] = ng + zg * (ev[q] - ng);
    }
  }

  // acc[q] = partial sum over this lane's 8 j's of e[i][j][kg*4+q]*A[i][j];
  // reduce over the 16 lanes of each kg-group.
#pragma unroll
  for (int m = 1; m <= 8; m <<= 1) {
#pragma unroll
    for (int q = 0; q < 4; ++q) acc[q] += __shfl_xor(acc[q], m, 64);
  }
  if (lj == 0) {
#pragma unroll
    for (int q = 0; q < 4; ++q) red[wid][kg * 4 + q] = acc[q];
  }
  __syncthreads();
  if (tid < 16)
    rowsum_part[(i * NSPLIT + s) * 16 + tid] =
        red[0][tid] + red[1][tid] + red[2][tid] + red[3][tid];
}

// Node GRU (32 threads per node, 8 nodes per block) + argmax in block 0 thread 0.
__global__ __launch_bounds__(256) void node_kernel(
    const float* __restrict__ obs, const float* __restrict__ h,
    const int* __restrict__ types, const float* __restrict__ w_ih_n,
    const float* __restrict__ w_hh_n, const float* __restrict__ b_n,
    const float* __restrict__ bn_n, const float* __restrict__ y,
    const float* __restrict__ rowsum_part, float* __restrict__ out) {
  const int tid = threadIdx.x;
  const int node = blockIdx.x * 8 + (tid >> 5);
  const int d = tid & 31;
  const int t = types[node];
  float x[16];
#pragma unroll
  for (int q = 0; q < 16; ++q) {
    const float* rp = rowsum_part + node * NSPLIT * 16 + q;
    float rs = rp[0] + rp[16];
    x[q] = y[node * 16 + q] * rs;
  }
  if (node < NOBS_) x[0] = obs[node];
  const float* wi = w_ih_n + t * 96 * 16;
  const float* wh = w_hh_n + t * 96 * 32;
  const float* hp = h + node * 32;
  float ir = b_n[t * 96 + d], iz = b_n[t * 96 + 32 + d], in_ = b_n[t * 96 + 64 + d];
#pragma unroll
  for (int q = 0; q < 16; ++q) {
    ir = fmaf(wi[d * 16 + q], x[q], ir);
    iz = fmaf(wi[(32 + d) * 16 + q], x[q], iz);
    in_ = fmaf(wi[(64 + d) * 16 + q], x[q], in_);
  }
  float hr = 0.0f, hz = 0.0f, hn = 0.0f;
#pragma unroll
  for (int q = 0; q < 32; ++q) {
    hr = fmaf(wh[d * 32 + q], hp[q], hr);
    hz = fmaf(wh[(32 + d) * 32 + q], hp[q], hz);
    hn = fmaf(wh[(64 + d) * 32 + q], hp[q], hn);
  }
  float rg = sig_(ir + hr), zg = sig_(iz + hz);
  float ng = tanh_(in_ + rg * (hn + bn_n[t * 32 + d]));
  out[1 + node * 32 + d] = ng + zg * (hp[d] - ng);

  if (blockIdx.x == 0 && tid == 0) {
    int bi = 0;
    float best = y[(NN - ADIM_) * 16];
    for (int l = 1; l < ADIM_; ++l) {
      float v = y[(NN - ADIM_ + l) * 16];
      if (v > best) { best = v; bi = l; }
    }
    out[0] = (float)bi;
  }
}

extern "C" void kernel_launch(void* const* d_in, const int* in_sizes, int n_in,
                              void* d_out, int out_size, void* d_ws, size_t ws_size,
                              hipStream_t stream) {
  const float* obs   = (const float*)d_in[0];
  const float* h     = (const float*)d_in[1];
  const int*   types = (const int*)d_in[2];
  const float* e     = (const float*)d_in[3];
  const int*   A     = (const int*)d_in[4];
  const float* r     = (const float*)d_in[5];
  const float* w_ih_n = (const float*)d_in[6];
  const float* w_hh_n = (const float*)d_in[7];
  const float* b_n    = (const float*)d_in[8];
  const float* bn_n   = (const float*)d_in[9];
  const float* W_out  = (const float*)d_in[10];
  const float* b_out  = (const float*)d_in[11];
  const float* w_ih_e = (const float*)d_in[12];
  const float* w_hh_e = (const float*)d_in[13];
  const float* b_e    = (const float*)d_in[14];
  const float* bn_e   = (const float*)d_in[15];

  float* ws = (float*)d_ws;
  float* y_buf       = ws;                     // 1024*16  f32
  float* base        = y_buf + 16384;          // 1024*48  f32
  float* rowsum_part = base + 49152;           // 1024*2*16 f32
  _Float16* y_h      = (_Float16*)(rowsum_part + 32768);  // 1024*16 f16

  float* out   = (float*)d_out;
  float* out_e = out + 1 + NN * DHH;           // e_new region (d_out + 32769)

  y_kernel<<<64, 256, 0, stream>>>(h, W_out, b_out, y_buf, y_h);
  prep_kernel<<<192, 256, 0, stream>>>(y_buf, types, w_ih_e, b_e, r, base);
  edge_kernel<<<NN * NSPLIT, 256, 0, stream>>>(e, A, w_hh_e, w_ih_e, bn_e, types,
                                               base, y_h, out_e, rowsum_part);
  node_kernel<<<128, 256, 0, stream>>>(obs, h, types, w_ih_n, w_hh_n, b_n, bn_n,
                                       y_buf, rowsum_part, out);
}

// Round 7
// 42.776 us; speedup vs baseline: 1.8403x; 1.0305x over previous
//
#include <hip/hip_runtime.h>
#include <math.h>

#define NN 1024
#define DHH 32
#define DEE 16
#define TT 8
#define NOBS_ 64
#define ADIM_ 10
#define NSPLIT 2   // blocks per row in edge kernel

typedef _Float16 h4 __attribute__((ext_vector_type(4)));
typedef float f4 __attribute__((ext_vector_type(4)));

// 1-ulp hardware reciprocal: avoids the ~10-instr IEEE division expansion.
__device__ __forceinline__ float rcp_(float x) { return __builtin_amdgcn_rcpf(x); }
__device__ __forceinline__ float sig_(float x) { return rcp_(1.0f + __expf(-x)); }
__device__ __forceinline__ float tanh_(float x) { return 1.0f - 2.0f * rcp_(1.0f + __expf(2.0f * x)); }

// y[i][d] = relu(h[i] . W_out[d] + b_out[d]); also emit f16 copy for MFMA B-frags.
__global__ __launch_bounds__(256) void y_kernel(const float* __restrict__ h,
                                                const float* __restrict__ W_out,
                                                const float* __restrict__ b_out,
                                                float* __restrict__ y,
                                                _Float16* __restrict__ y_h) {
  int gid = blockIdx.x * 256 + threadIdx.x;
  int i = gid >> 4, d = gid & 15;
  const float* hp = h + i * DHH;
  const float* wp = W_out + d * DHH;
  float s = b_out[d];
#pragma unroll
  for (int q = 0; q < DHH; ++q) s = fmaf(hp[q], wp[q], s);
  s = fmaxf(s, 0.0f);
  y[gid] = s;
  y_h[gid] = (_Float16)s;
}

// base[i][k] = b_e[t_i][k] + r*w_ih_e[t_i][k][32] + sum_d w_ih_e[t_i][k][d]*y[i][d]
__global__ __launch_bounds__(256) void prep_kernel(const float* __restrict__ y,
                                                   const int* __restrict__ types,
                                                   const float* __restrict__ w_ih_e,
                                                   const float* __restrict__ b_e,
                                                   const float* __restrict__ rs,
                                                   float* __restrict__ base) {
  int gid = blockIdx.x * 256 + threadIdx.x;
  int i = gid / 48, k = gid - (gid / 48) * 48;
  int t = types[i];
  const float* w = w_ih_e + (t * 48 + k) * 33;
  const float* yp = y + i * DEE;
  float s = b_e[t * 48 + k] + rs[0] * w[32];
#pragma unroll
  for (int q = 0; q < DEE; ++q) s = fmaf(w[q], yp[q], s);
  base[gid] = s;
}

// MFMA edge GRU, gj folded into matrix pipe. Block b: row i = b>>1, half s = b&1.
// Load phase issues all 8 tiles' loads (static unrolled arrays -> registers),
// compute phase runs 6 MFMAs + gates per tile. One latency for the whole block.
__global__ __launch_bounds__(256, 4) void edge_kernel(
    const float* __restrict__ e, const int* __restrict__ A,
    const float* __restrict__ w_hh_e, const float* __restrict__ w_ih_e,
    const float* __restrict__ bn_e, const int* __restrict__ types,
    const float* __restrict__ base, const _Float16* __restrict__ yh,
    float* __restrict__ e_new, float* __restrict__ rowsum_part) {
  __shared__ float red[4][16];
  const int b = blockIdx.x;
  const int i = b >> 1;
  const int s = b & 1;
  const int tid = threadIdx.x;
  const int lane = tid & 63, wid = tid >> 6;
  const int lj = lane & 15;   // edge index within tile (A/B N-index, D col)
  const int kg = lane >> 4;   // K chunk (A/B), dim chunk (D rows)
  const int t = types[i];

  // hh A-frags: W_hh[gate*16+lj][kg*4+q]  (contiguous -> f4 loads)
  const float* Wt = w_hh_e + t * 768;
  h4 ar, az, an;
  {
    f4 vr = *(const f4*)(Wt + lj * 16 + kg * 4);
    f4 vz = *(const f4*)(Wt + (16 + lj) * 16 + kg * 4);
    f4 vn = *(const f4*)(Wt + (32 + lj) * 16 + kg * 4);
#pragma unroll
    for (int q = 0; q < 4; ++q) {
      ar[q] = (_Float16)vr[q]; az[q] = (_Float16)vz[q]; an[q] = (_Float16)vn[q];
    }
  }
  // ih(y_j) A-frags: w_ih_e[t][gate*16+lj][16 + kg*4+q]  (row stride 33)
  const float* W2 = w_ih_e + t * 48 * 33 + 16;
  h4 cr, cz, cn;
#pragma unroll
  for (int q = 0; q < 4; ++q) {
    cr[q] = (_Float16)W2[lj * 33 + kg * 4 + q];
    cz[q] = (_Float16)W2[(16 + lj) * 33 + kg * 4 + q];
    cn[q] = (_Float16)W2[(32 + lj) * 33 + kg * 4 + q];
  }

  const f4 bsr = *(const f4*)(base + i * 48 + kg * 4);
  const f4 bsz = *(const f4*)(base + i * 48 + 16 + kg * 4);
  const f4 bsn = *(const f4*)(base + i * 48 + 32 + kg * 4);
  const f4 bnv = *(const f4*)(bn_e + t * 16 + kg * 4);

  const int jb = s * 512 + wid * 128 + lj;   // this lane's edge for tile tt is jb + tt*16
  const int erow = i * NN;                   // 32-bit offsets throughout the hot loop
  f4 acc = {0.0f, 0.0f, 0.0f, 0.0f};
  const f4 zero = {0.0f, 0.0f, 0.0f, 0.0f};

  // ---- load phase: all 8 tiles in flight (56 VGPRs of load data) ----
  f4 evs[8]; h4 yvs[8]; float as[8];
#pragma unroll
  for (int tt = 0; tt < 8; ++tt) {
    const int j = jb + tt * 16;
    evs[tt] = *(const f4*)(e + (erow + j) * 16 + kg * 4);
    yvs[tt] = *(const h4*)(yh + j * 16 + kg * 4);
    as[tt] = (float)A[erow + j];
  }

  // ---- compute phase ----
#pragma unroll
  for (int tt = 0; tt < 8; ++tt) {
    const f4 ev = evs[tt];
    const h4 yv = yvs[tt];
    const float aij = as[tt];

    h4 bf;
#pragma unroll
    for (int q = 0; q < 4; ++q) bf[q] = (_Float16)ev[q];

    f4 dr = __builtin_amdgcn_mfma_f32_16x16x16f16(ar, bf, zero, 0, 0, 0);
    f4 dz = __builtin_amdgcn_mfma_f32_16x16x16f16(az, bf, zero, 0, 0, 0);
    f4 dh = __builtin_amdgcn_mfma_f32_16x16x16f16(an, bf, zero, 0, 0, 0);
    dr = __builtin_amdgcn_mfma_f32_16x16x16f16(cr, yv, dr, 0, 0, 0);
    dz = __builtin_amdgcn_mfma_f32_16x16x16f16(cz, yv, dz, 0, 0, 0);
    const f4 di = __builtin_amdgcn_mfma_f32_16x16x16f16(cn, yv, zero, 0, 0, 0);

#pragma unroll
    for (int q = 0; q < 4; ++q) acc[q] = fmaf(ev[q], aij, acc[q]);

    float* op = e_new + (erow + jb + tt * 16) * 16 + kg * 4;
#pragma unroll
    for (int q = 0; q < 4; ++q) {
      const float rg = sig_(bsr[q] + dr[q]);
      const float zg = sig_(bsz[q] + dz[q]);
      const float ng = tanh_(bsn[q] + di[q] + rg * (dh[q] + bnv[q]));
      op[q] = ng + zg * (ev[q] - ng);
    }
  }

  // acc[q] = partial sum over this lane's 8 j's of e[i][j][kg*4+q]*A[i][j];
  // reduce over the 16 lanes of each kg-group.
#pragma unroll
  for (int m = 1; m <= 8; m <<= 1) {
#pragma unroll
    for (int q = 0; q < 4; ++q) acc[q] += __shfl_xor(acc[q], m, 64);
  }
  if (lj == 0) {
#pragma unroll
    for (int q = 0; q < 4; ++q) red[wid][kg * 4 + q] = acc[q];
  }
  __syncthreads();
  if (tid < 16)
    rowsum_part[(i * NSPLIT + s) * 16 + tid] =
        red[0][tid] + red[1][tid] + red[2][tid] + red[3][tid];
}

// Node GRU (32 threads per node, 8 nodes per block) + argmax in block 0 thread 0.
__global__ __launch_bounds__(256) void node_kernel(
    const float* __restrict__ obs, const float* __restrict__ h,
    const int* __restrict__ types, const float* __restrict__ w_ih_n,
    const float* __restrict__ w_hh_n, const float* __restrict__ b_n,
    const float* __restrict__ bn_n, const float* __restrict__ y,
    const float* __restrict__ rowsum_part, float* __restrict__ out) {
  const int tid = threadIdx.x;
  const int node = blockIdx.x * 8 + (tid >> 5);
  const int d = tid & 31;
  const int t = types[node];
  float x[16];
#pragma unroll
  for (int q = 0; q < 16; ++q) {
    const float* rp = rowsum_part + node * NSPLIT * 16 + q;
    float rs = rp[0] + rp[16];
    x[q] = y[node * 16 + q] * rs;
  }
  if (node < NOBS_) x[0] = obs[node];
  const float* wi = w_ih_n + t * 96 * 16;
  const float* wh = w_hh_n + t * 96 * 32;
  const float* hp = h + node * 32;
  float ir = b_n[t * 96 + d], iz = b_n[t * 96 + 32 + d], in_ = b_n[t * 96 + 64 + d];
#pragma unroll
  for (int q = 0; q < 16; ++q) {
    ir = fmaf(wi[d * 16 + q], x[q], ir);
    iz = fmaf(wi[(32 + d) * 16 + q], x[q], iz);
    in_ = fmaf(wi[(64 + d) * 16 + q], x[q], in_);
  }
  float hr = 0.0f, hz = 0.0f, hn = 0.0f;
#pragma unroll
  for (int q = 0; q < 32; ++q) {
    hr = fmaf(wh[d * 32 + q], hp[q], hr);
    hz = fmaf(wh[(32 + d) * 32 + q], hp[q], hz);
    hn = fmaf(wh[(64 + d) * 32 + q], hp[q], hn);
  }
  float rg = sig_(ir + hr), zg = sig_(iz + hz);
  float ng = tanh_(in_ + rg * (hn + bn_n[t * 32 + d]));
  out[1 + node * 32 + d] = ng + zg * (hp[d] - ng);

  if (blockIdx.x == 0 && tid == 0) {
    int bi = 0;
    float best = y[(NN - ADIM_) * 16];
    for (int l = 1; l < ADIM_; ++l) {
      float v = y[(NN - ADIM_ + l) * 16];
      if (v > best) { best = v; bi = l; }
    }
    out[0] = (float)bi;
  }
}

extern "C" void kernel_launch(void* const* d_in, const int* in_sizes, int n_in,
                              void* d_out, int out_size, void* d_ws, size_t ws_size,
                              hipStream_t stream) {
  const float* obs   = (const float*)d_in[0];
  const float* h     = (const float*)d_in[1];
  const int*   types = (const int*)d_in[2];
  const float* e     = (const float*)d_in[3];
  const int*   A     = (const int*)d_in[4];
  const float* r     = (const float*)d_in[5];
  const float* w_ih_n = (const float*)d_in[6];
  const float* w_hh_n = (const float*)d_in[7];
  const float* b_n    = (const float*)d_in[8];
  const float* bn_n   = (const float*)d_in[9];
  const float* W_out  = (const float*)d_in[10];
  const float* b_out  = (const float*)d_in[11];
  const float* w_ih_e = (const float*)d_in[12];
  const float* w_hh_e = (const float*)d_in[13];
  const float* b_e    = (const float*)d_in[14];
  const float* bn_e   = (const float*)d_in[15];

  float* ws = (float*)d_ws;
  float* y_buf       = ws;                     // 1024*16  f32
  float* base        = y_buf + 16384;          // 1024*48  f32
  float* rowsum_part = base + 49152;           // 1024*2*16 f32
  _Float16* y_h      = (_Float16*)(rowsum_part + 32768);  // 1024*16 f16

  float* out   = (float*)d_out;
  float* out_e = out + 1 + NN * DHH;           // e_new region (d_out + 32769)

  y_kernel<<<64, 256, 0, stream>>>(h, W_out, b_out, y_buf, y_h);
  prep_kernel<<<192, 256, 0, stream>>>(y_buf, types, w_ih_e, b_e, r, base);
  edge_kernel<<<NN * NSPLIT, 256, 0, stream>>>(e, A, w_hh_e, w_ih_e, bn_e, types,
                                               base, y_h, out_e, rowsum_part);
  node_kernel<<<128, 256, 0, stream>>>(obs, h, types, w_ih_n, w_hh_n, b_n, bn_n,
                                       y_buf, rowsum_part, out);
}